// Round 2
// baseline (211.712 us; speedup 1.0000x reference)
//
#include <hip/hip_runtime.h>

#define HID 16
#define SB_BITS 11
#define SBLK (1 << SB_BITS)            // 2048 dst per block-range
#define NBMAX 64
#define GSTRIDE 16                     // gcurA: one counter per 64B line
#define PT_THREADS 512
#define PT_K 8
#define PT_EDGES (PT_THREADS * PT_K)   // 4096 edges per partition tile

// ---------------- init: zero cursors + atomic agg targets ----------------
__global__ void k_init(int* __restrict__ p, int n) {
    int i = blockIdx.x * blockDim.x + threadIdx.x;
    if (i < n) p[i] = 0;
}

// ---------------- pass A: bin edges by dst-block; payload (dloc11<<17)|src17 --
// per-thread consecutive 8-edge strip, read as 2x uint4 per array
__global__ void __launch_bounds__(PT_THREADS)
k_passA(const int* __restrict__ src, const int* __restrict__ dst,
        unsigned* __restrict__ bucketsA, int* __restrict__ gcurA,
        int E, int nb, int capA) {
    __shared__ int cnt[NBMAX];
    __shared__ int pos[NBMAX];
    __shared__ int gbase[NBMAX];
    __shared__ unsigned reorder[PT_EDGES];
    __shared__ unsigned char bbk[PT_EDGES];
    int tb = blockIdx.x * PT_EDGES;
    int nE = min(PT_EDGES, E - tb);
    if (threadIdx.x < nb) cnt[threadIdx.x] = 0;
    __syncthreads();
    int kk[PT_K]; int rk[PT_K]; unsigned pk[PT_K];
    int ebase = tb + threadIdx.x * PT_K;
    if (ebase + PT_K <= E) {
        uint4 s0 = *(const uint4*)(src + ebase);
        uint4 s1 = *(const uint4*)(src + ebase + 4);
        uint4 d0 = *(const uint4*)(dst + ebase);
        uint4 d1 = *(const uint4*)(dst + ebase + 4);
        int ss[PT_K] = {(int)s0.x,(int)s0.y,(int)s0.z,(int)s0.w,
                        (int)s1.x,(int)s1.y,(int)s1.z,(int)s1.w};
        int dd[PT_K] = {(int)d0.x,(int)d0.y,(int)d0.z,(int)d0.w,
                        (int)d1.x,(int)d1.y,(int)d1.z,(int)d1.w};
#pragma unroll
        for (int k = 0; k < PT_K; k++) {
            int b = dd[k] >> SB_BITS;
            kk[k] = b;
            pk[k] = ((unsigned)(dd[k] & (SBLK - 1)) << 17) | (unsigned)ss[k];
            rk[k] = atomicAdd(&cnt[b], 1);
        }
    } else {
#pragma unroll
        for (int k = 0; k < PT_K; k++) {
            int e = ebase + k;
            if (e < E) {
                int s = src[e], d = dst[e];
                int b = d >> SB_BITS;
                kk[k] = b;
                pk[k] = ((unsigned)(d & (SBLK - 1)) << 17) | (unsigned)s;
                rk[k] = atomicAdd(&cnt[b], 1);
            } else kk[k] = -1;
        }
    }
    __syncthreads();
    if (threadIdx.x == 0) {
        int acc = 0;
        for (int b = 0; b < nb; b++) { pos[b] = acc; acc += cnt[b]; }
    }
    __syncthreads();
    if (threadIdx.x < nb && cnt[threadIdx.x] > 0)
        gbase[threadIdx.x] = atomicAdd(&gcurA[threadIdx.x * GSTRIDE], cnt[threadIdx.x]);
    __syncthreads();
#pragma unroll
    for (int k = 0; k < PT_K; k++) {
        if (kk[k] >= 0) {
            int idx = pos[kk[k]] + rk[k];
            reorder[idx] = pk[k];
            bbk[idx] = (unsigned char)kk[k];
        }
    }
    __syncthreads();
    for (int idx = threadIdx.x; idx < nE; idx += PT_THREADS) {
        int b = bbk[idx];
        int g = gbase[b] + (idx - pos[b]);
        if (g < capA) bucketsA[(size_t)b * capA + g] = reorder[idx];
    }
}

// ---------------- agg over bucketsA tiles: scalar values --------------------
// per block: 2048-slot LDS accumulator (dloc), ds_add_f32 per edge,
// coalesced global atomic flush. val[src] gather is L2-resident.
__global__ void __launch_bounds__(PT_THREADS)
k_aggA1(const unsigned* __restrict__ bucketsA, const int* __restrict__ gcurA,
        const float* __restrict__ val, float* __restrict__ AGG,
        int capA, int tilesA, int N) {
    int j = blockIdx.x / tilesA;
    int tile = blockIdx.x - j * tilesA;
    int cnt_j = min(gcurA[j * GSTRIDE], capA);
    int tb = tile * PT_EDGES;
    if (tb >= cnt_j) return;                    // block-uniform
    int nE = min(PT_EDGES, cnt_j - tb);
    __shared__ float acc[SBLK];
    for (int i = threadIdx.x; i < SBLK; i += PT_THREADS) acc[i] = 0.f;
    __syncthreads();
    const unsigned* in = bucketsA + (size_t)j * capA + tb;
    int ebase = threadIdx.x * PT_K;
    if (ebase + PT_K <= nE) {
        uint4 p0 = *(const uint4*)(in + ebase);
        uint4 p1 = *(const uint4*)(in + ebase + 4);
        unsigned pp[PT_K] = {p0.x, p0.y, p0.z, p0.w, p1.x, p1.y, p1.z, p1.w};
        float v[PT_K];
#pragma unroll
        for (int k = 0; k < PT_K; k++) v[k] = val[pp[k] & 0x1FFFFu];
#pragma unroll
        for (int k = 0; k < PT_K; k++) atomicAdd(&acc[pp[k] >> 17], v[k]);
    } else {
#pragma unroll
        for (int k = 0; k < PT_K; k++) {
            int e = ebase + k;
            if (e < nE) {
                unsigned p = in[e];
                atomicAdd(&acc[p >> 17], val[p & 0x1FFFFu]);
            }
        }
    }
    __syncthreads();
    int base_n = j << SB_BITS;
    for (int i = threadIdx.x; i < SBLK; i += PT_THREADS) {
        float v = acc[i];
        int n = base_n + i;
        if (n < N && v != 0.f) atomicAdd(&AGG[n], v);
    }
}

// ---------------- agg over bucketsA tiles: float2 values --------------------
__global__ void __launch_bounds__(PT_THREADS)
k_aggA2(const unsigned* __restrict__ bucketsA, const int* __restrict__ gcurA,
        const float* __restrict__ SAB, float* __restrict__ AGG2,
        int capA, int tilesA, int N) {
    int j = blockIdx.x / tilesA;
    int tile = blockIdx.x - j * tilesA;
    int cnt_j = min(gcurA[j * GSTRIDE], capA);
    int tb = tile * PT_EDGES;
    if (tb >= cnt_j) return;
    int nE = min(PT_EDGES, cnt_j - tb);
    __shared__ float accx[SBLK];
    __shared__ float accy[SBLK];
    for (int i = threadIdx.x; i < SBLK; i += PT_THREADS) { accx[i] = 0.f; accy[i] = 0.f; }
    __syncthreads();
    const unsigned* in = bucketsA + (size_t)j * capA + tb;
    const float2* v2 = (const float2*)SAB;
    int ebase = threadIdx.x * PT_K;
    if (ebase + PT_K <= nE) {
        uint4 p0 = *(const uint4*)(in + ebase);
        uint4 p1 = *(const uint4*)(in + ebase + 4);
        unsigned pp[PT_K] = {p0.x, p0.y, p0.z, p0.w, p1.x, p1.y, p1.z, p1.w};
        float2 v[PT_K];
#pragma unroll
        for (int k = 0; k < PT_K; k++) v[k] = v2[pp[k] & 0x1FFFFu];
#pragma unroll
        for (int k = 0; k < PT_K; k++) {
            int d = (int)(pp[k] >> 17);
            atomicAdd(&accx[d], v[k].x);
            atomicAdd(&accy[d], v[k].y);
        }
    } else {
#pragma unroll
        for (int k = 0; k < PT_K; k++) {
            int e = ebase + k;
            if (e < nE) {
                unsigned p = in[e];
                float2 v = v2[p & 0x1FFFFu];
                int d = (int)(p >> 17);
                atomicAdd(&accx[d], v.x);
                atomicAdd(&accy[d], v.y);
            }
        }
    }
    __syncthreads();
    int base_n = j << SB_BITS;
    for (int i = threadIdx.x; i < SBLK; i += PT_THREADS) {
        float vx = accx[i], vy = accy[i];
        int n = base_n + i;
        if (n < N && (vx != 0.f || vy != 0.f)) {
            atomicAdd(&AGG2[2 * n],     vx);
            atomicAdd(&AGG2[2 * n + 1], vy);
        }
    }
}

// ---------------- node-wise encode: z=relu(a1*wr + x*wo + b), project -------
// u1=Wp_rel.wd_rel, u2=Wp_rel.wd_root, v1=Wp_root.wd_rel, v2=Wp_root.wd_root
__global__ void __launch_bounds__(256)
k_enc(const float* __restrict__ AGG1, const float* __restrict__ x,
      const float* __restrict__ ewrel, const float* __restrict__ ewroot,
      const float* __restrict__ eb,
      const float* __restrict__ pwrel, const float* __restrict__ pwroot,
      const float* __restrict__ dwrel, const float* __restrict__ dwroot,
      float* __restrict__ SAB, float* __restrict__ G1, float* __restrict__ G2,
      int N) {
    __shared__ float su1[HID], su2[HID], sv1[HID], sv2[HID];
    __shared__ float swr[HID], swo[HID], sbb[HID];
    int t = threadIdx.x;
    if (t < 64) {
        int k = t & 15, w = t >> 4;
        const float* M  = (w < 2) ? pwrel : pwroot;
        const float* vv = ((w & 1) == 0) ? dwrel : dwroot;
        float acc = 0.f;
        for (int h = 0; h < HID; h++) acc += M[k * HID + h] * vv[h];
        if (w == 0) su1[k] = acc;
        else if (w == 1) su2[k] = acc;
        else if (w == 2) sv1[k] = acc;
        else sv2[k] = acc;
    }
    if (t < HID) { swr[t] = ewrel[t]; swo[t] = ewroot[t]; sbb[t] = eb[t]; }
    __syncthreads();
    int n = blockIdx.x * 256 + t;
    if (n < N) {
        float a1 = AGG1[n], xi = x[n];
        float sa = 0.f, sb = 0.f, g1 = 0.f, g2 = 0.f;
#pragma unroll
        for (int h = 0; h < HID; h++) {
            float z = fmaxf(fmaf(a1, swr[h], fmaf(xi, swo[h], sbb[h])), 0.f);
            sa = fmaf(z, su1[h], sa);
            sb = fmaf(z, su2[h], sb);
            g1 = fmaf(z, sv1[h], g1);
            g2 = fmaf(z, sv2[h], g2);
        }
        ((float2*)SAB)[n] = make_float2(sa, sb);
        G1[n] = g1; G2[n] = g2;
    }
}

// ---------------- node-wise mid: BETA/R from AGG2 ---------------------------
__global__ void __launch_bounds__(256)
k_mid(const float* __restrict__ AGG2, const float* __restrict__ G1,
      const float* __restrict__ G2, const float* __restrict__ pb,
      const float* __restrict__ dwrel, const float* __restrict__ dwroot,
      const float* __restrict__ db,
      float* __restrict__ BETA, float* __restrict__ R, int N) {
    __shared__ float sc1, sc2, sbd;
    if (threadIdx.x == 0) {
        float c1 = 0.f, c2 = 0.f;
        for (int h = 0; h < HID; h++) { c1 += pb[h] * dwrel[h]; c2 += pb[h] * dwroot[h]; }
        sc1 = c1; sc2 = c2; sbd = db[0];
    }
    __syncthreads();
    int n = blockIdx.x * 256 + threadIdx.x;
    if (n < N) {
        float2 a = ((const float2*)AGG2)[n];
        BETA[n] = a.x + G1[n] + sc1;
        R[n]    = a.y + G2[n] + sc2 + sbd;
    }
}

// ---------------- node-wise final: out = relu(agg3 + R) ---------------------
__global__ void __launch_bounds__(256)
k_final(const float* __restrict__ AGG3, const float* __restrict__ R,
        float* __restrict__ out, int N) {
    int n = blockIdx.x * 256 + threadIdx.x;
    if (n < N) out[n] = fmaxf(AGG3[n] + R[n], 0.f);
}

// ---------------- launch ----------------
extern "C" void kernel_launch(void* const* d_in, const int* in_sizes, int n_in,
                              void* d_out, int out_size, void* d_ws, size_t ws_size,
                              hipStream_t stream) {
    const float* x      = (const float*)d_in[0];
    const int*   ei     = (const int*)d_in[1];
    const float* ewrel  = (const float*)d_in[2];
    const float* ewroot = (const float*)d_in[3];
    const float* eb     = (const float*)d_in[4];
    const float* pwrel  = (const float*)d_in[5];
    const float* pwroot = (const float*)d_in[6];
    const float* pb     = (const float*)d_in[7];
    const float* dwrel  = (const float*)d_in[8];
    const float* dwroot = (const float*)d_in[9];
    const float* db     = (const float*)d_in[10];
    float* out = (float*)d_out;

    const int N = in_sizes[0];
    const int E = in_sizes[1] / 2;
    const int* src = ei;
    const int* dst = ei + E;

    const int nb = (N + SBLK - 1) >> SB_BITS;                  // 49
    int capA = ((E / nb + 2048) + PT_EDGES - 1) & ~(PT_EDGES - 1);   // 69632
    const int tilesA = capA / PT_EDGES;                        // 17

    // workspace layout (4-byte words); atomic targets contiguous for zeroing
    size_t off = 0;
    int* gcurA = (int*)d_ws;                    off += NBMAX * GSTRIDE;   // 1024
    float* AGG1 = (float*)d_ws + off;           off += N;
    float* AGG2 = (float*)d_ws + off;           off += (size_t)2 * N;
    float* AGG3 = (float*)d_ws + off;           off += N;
    const int zeroWords = (int)off;
    off = (off + 255) & ~(size_t)255;
    unsigned* bucketsA = (unsigned*)d_ws + off; off += (size_t)nb * capA;
    float* SAB  = (float*)d_ws + off;           off += (size_t)2 * N;
    float* G1   = (float*)d_ws + off;           off += N;
    float* G2   = (float*)d_ws + off;           off += N;
    float* BETA = (float*)d_ws + off;           off += N;
    float* R    = (float*)d_ws + off;           off += N;

    const int ntilesA = (E + PT_EDGES - 1) / PT_EDGES;          // 782
    const int aggGrid = nb * tilesA;                            // 833
    const int nodeBlocks = (N + 255) / 256;                     // 391

    hipLaunchKernelGGL(k_init, dim3((zeroWords + 255) / 256), dim3(256), 0, stream,
                       gcurA, zeroWords);
    hipLaunchKernelGGL(k_passA, dim3(ntilesA), dim3(PT_THREADS), 0, stream,
                       src, dst, bucketsA, gcurA, E, nb, capA);

    // layer 1: agg(x) -> AGG1 ; encode -> SAB, G1, G2
    hipLaunchKernelGGL(k_aggA1, dim3(aggGrid), dim3(PT_THREADS), 0, stream,
                       bucketsA, gcurA, x, AGG1, capA, tilesA, N);
    hipLaunchKernelGGL(k_enc, dim3(nodeBlocks), dim3(256), 0, stream,
                       AGG1, x, ewrel, ewroot, eb, pwrel, pwroot,
                       dwrel, dwroot, SAB, G1, G2, N);

    // layer 2: agg(SAB) -> AGG2 ; mid -> BETA, R
    hipLaunchKernelGGL(k_aggA2, dim3(aggGrid), dim3(PT_THREADS), 0, stream,
                       bucketsA, gcurA, SAB, AGG2, capA, tilesA, N);
    hipLaunchKernelGGL(k_mid, dim3(nodeBlocks), dim3(256), 0, stream,
                       AGG2, G1, G2, pb, dwrel, dwroot, db, BETA, R, N);

    // layer 3: agg(BETA) -> AGG3 ; final
    hipLaunchKernelGGL(k_aggA1, dim3(aggGrid), dim3(PT_THREADS), 0, stream,
                       bucketsA, gcurA, BETA, AGG3, capA, tilesA, N);
    hipLaunchKernelGGL(k_final, dim3(nodeBlocks), dim3(256), 0, stream,
                       AGG3, R, out, N);
}